// Round 1
// baseline (879.301 us; speedup 1.0000x reference)
//
#include <hip/hip_runtime.h>

#define BLK 256
#define F_INK 18
#define F_HIDK 16

__global__ void k_deg_init(float* __restrict__ deg, int n) {
  int i = blockIdx.x * BLK + threadIdx.x;
  if (i < n) deg[i] = 1.0f;  // self-loop contributes 1 to every node's degree
}

__global__ void k_deg_count(const int* __restrict__ col, float* __restrict__ deg, int e) {
  int i = blockIdx.x * BLK + threadIdx.x;
  if (i < e) atomicAdd(&deg[col[i]], 1.0f);
}

// Per node: dis = rsqrt(deg); hw1 = x @ W1; s1 = hw1 * dis
__global__ void k_node1(const float* __restrict__ x, const float* __restrict__ W1,
                        float* __restrict__ degdis, float* __restrict__ s1, int n) {
  __shared__ float sx[BLK * F_INK];
  const int base = blockIdx.x * BLK;
  const int gbase = base * F_INK;
  const int lim = n * F_INK;
  for (int t = threadIdx.x; t < BLK * F_INK; t += BLK) {
    int gi = gbase + t;
    sx[t] = (gi < lim) ? x[gi] : 0.0f;
  }
  __syncthreads();
  int i = base + threadIdx.x;
  if (i >= n) return;
  float di = rsqrtf(degdis[i]);
  degdis[i] = di;  // in-place deg -> dis, own slot only
  float hw[F_HIDK];
#pragma unroll
  for (int f = 0; f < F_HIDK; ++f) hw[f] = 0.0f;
  const float* xi = &sx[threadIdx.x * F_INK];
#pragma unroll
  for (int k = 0; k < F_INK; ++k) {
    float xk = xi[k];
#pragma unroll
    for (int f = 0; f < F_HIDK; ++f) hw[f] = fmaf(xk, W1[k * F_HIDK + f], hw[f]);
  }
  float4* o = (float4*)&s1[(size_t)i * F_HIDK];
#pragma unroll
  for (int q = 0; q < 4; ++q) {
    float4 v;
    v.x = hw[q * 4 + 0] * di;
    v.y = hw[q * 4 + 1] * di;
    v.z = hw[q * 4 + 2] * di;
    v.w = hw[q * 4 + 3] * di;
    o[q] = v;
  }
}

// 16 lanes per edge: gather s1[row] (one 64B line), atomicAdd into agg1[col]
__global__ void k_scatter1(const int* __restrict__ rows, const int* __restrict__ cols,
                           const float* __restrict__ s1, float* __restrict__ agg1,
                           int e) {
  long long t = (long long)blockIdx.x * BLK + threadIdx.x;
  int eid = (int)(t >> 4);
  if (eid >= e) return;
  int f = (int)(t & 15);
  int r = rows[eid];
  int c = cols[eid];
  atomicAdd(&agg1[(size_t)c * F_HIDK + f], s1[(size_t)r * F_HIDK + f]);
}

// Per node: h = relu(dis*(agg1 + s1_self) + b1); o = h @ W2; s2 = o * dis
__global__ void k_node2(const float* __restrict__ agg1, const float* __restrict__ s1,
                        const float* __restrict__ dis, const float* __restrict__ b1,
                        const float* __restrict__ W2, float* __restrict__ s2, int n) {
  int i = blockIdx.x * BLK + threadIdx.x;
  if (i >= n) return;
  float di = dis[i];
  const float4* a4 = (const float4*)&agg1[(size_t)i * F_HIDK];
  const float4* s4 = (const float4*)&s1[(size_t)i * F_HIDK];
  float o0 = 0.f, o1 = 0.f;
#pragma unroll
  for (int q = 0; q < 4; ++q) {
    float4 a = a4[q];
    float4 s = s4[q];
    float va[4] = {a.x + s.x, a.y + s.y, a.z + s.z, a.w + s.w};
#pragma unroll
    for (int j = 0; j < 4; ++j) {
      int f = q * 4 + j;
      float h = fmaxf(fmaf(di, va[j], b1[f]), 0.0f);
      o0 = fmaf(h, W2[f * 2 + 0], o0);
      o1 = fmaf(h, W2[f * 2 + 1], o1);
    }
  }
  float2 v;
  v.x = o0 * di;
  v.y = o1 * di;
  ((float2*)s2)[i] = v;
}

__global__ void k_scatter2(const int* __restrict__ rows, const int* __restrict__ cols,
                           const float* __restrict__ s2, float* __restrict__ agg2, int e) {
  int eid = blockIdx.x * BLK + threadIdx.x;
  if (eid >= e) return;
  int r = rows[eid];
  int c = cols[eid];
  float2 v = ((const float2*)s2)[r];
  atomicAdd(&agg2[(size_t)c * 2 + 0], v.x);
  atomicAdd(&agg2[(size_t)c * 2 + 1], v.y);
}

__global__ void k_out(const float* __restrict__ agg2, const float* __restrict__ s2,
                      const float* __restrict__ dis, const float* __restrict__ b2,
                      float* __restrict__ out, int n) {
  int i = blockIdx.x * BLK + threadIdx.x;
  if (i >= n) return;
  float di = dis[i];
  float2 a = ((const float2*)agg2)[i];
  float2 s = ((const float2*)s2)[i];
  float o0 = fmaf(di, a.x + s.x, b2[0]);
  float o1 = fmaf(di, a.y + s.y, b2[1]);
  float m = fmaxf(o0, o1);
  float lse = m + logf(expf(o0 - m) + expf(o1 - m));
  float2 r;
  r.x = o0 - lse;
  r.y = o1 - lse;
  ((float2*)out)[i] = r;
}

extern "C" void kernel_launch(void* const* d_in, const int* in_sizes, int n_in,
                              void* d_out, int out_size, void* d_ws, size_t ws_size,
                              hipStream_t stream) {
  const float* x  = (const float*)d_in[0];
  const float* W1 = (const float*)d_in[1];
  const float* b1 = (const float*)d_in[2];
  const float* W2 = (const float*)d_in[3];
  const float* b2 = (const float*)d_in[4];
  const int*   ei = (const int*)d_in[5];
  const int n = in_sizes[0] / F_INK;
  const int e = in_sizes[5] / 2;
  const int* rows = ei;       // edge_index[0] = source
  const int* cols = ei + e;   // edge_index[1] = target

  char* ws = (char*)d_ws;
  size_t off = 0;
  float* dis  = (float*)(ws + off); off += (size_t)n * 4;            // 4 MB
  float* s1   = (float*)(ws + off); off += (size_t)n * F_HIDK * 4;   // 64 MB
  float* agg1 = (float*)(ws + off); off += (size_t)n * F_HIDK * 4;   // 64 MB
  float* s2   = (float*)(ws + off); off += (size_t)n * 2 * 4;        // 8 MB
  float* agg2 = (float*)(ws + off); off += (size_t)n * 2 * 4;        // 8 MB
  float* outp = (float*)d_out;

  hipMemsetAsync(agg1, 0, (size_t)n * F_HIDK * 4, stream);
  hipMemsetAsync(agg2, 0, (size_t)n * 2 * 4, stream);

  int gn = (n + BLK - 1) / BLK;
  int ge = (e + BLK - 1) / BLK;
  long long t1 = (long long)e * 16;
  int gs1 = (int)((t1 + BLK - 1) / BLK);

  k_deg_init<<<gn, BLK, 0, stream>>>(dis, n);
  k_deg_count<<<ge, BLK, 0, stream>>>(cols, dis, e);
  k_node1<<<gn, BLK, 0, stream>>>(x, W1, dis, s1, n);
  k_scatter1<<<gs1, BLK, 0, stream>>>(rows, cols, s1, agg1, e);
  k_node2<<<gn, BLK, 0, stream>>>(agg1, s1, dis, b1, W2, s2, n);
  k_scatter2<<<ge, BLK, 0, stream>>>(rows, cols, s2, agg2, e);
  k_out<<<gn, BLK, 0, stream>>>(agg2, s2, dis, b2, outp, n);
}

// Round 2
// 565.438 us; speedup vs baseline: 1.5551x; 1.5551x over previous
//
#include <hip/hip_runtime.h>

#define BLK 256
#define F_INK 18
#define F_HIDK 16
#define NPB 1024          // nodes per bucket
#define EPB 4096          // edges per partition block (256 thr * 16)

// ---------- partition: histogram (bucket-major counts matrix) ----------
__global__ void k_hist(const int* __restrict__ cols, int* __restrict__ counts,
                       int e, int NB, int nblk) {
  __shared__ int hist[NPB];
  for (int j = threadIdx.x; j < NB; j += BLK) hist[j] = 0;
  __syncthreads();
  const int base = blockIdx.x * EPB;
#pragma unroll
  for (int k = 0; k < 16; ++k) {
    int i = base + k * BLK + threadIdx.x;
    if (i < e) atomicAdd(&hist[cols[i] >> 10], 1);
  }
  __syncthreads();
  for (int b = threadIdx.x; b < NB; b += BLK)
    counts[(size_t)b * nblk + blockIdx.x] = hist[b];
}

// ---------- device-wide exclusive scan over counts (L elements) ----------
__global__ void k_scanA(int* __restrict__ data, int* __restrict__ tot, int L) {
  __shared__ int sm[BLK];
  const int base = blockIdx.x * (BLK * 16) + threadIdx.x * 16;
  int v[16];
  int sum = 0;
#pragma unroll
  for (int j = 0; j < 16; ++j) {
    int idx = base + j;
    v[j] = (idx < L) ? data[idx] : 0;
    sum += v[j];
  }
  sm[threadIdx.x] = sum;
  __syncthreads();
  for (int off = 1; off < BLK; off <<= 1) {
    int t = (threadIdx.x >= off) ? sm[threadIdx.x - off] : 0;
    __syncthreads();
    sm[threadIdx.x] += t;
    __syncthreads();
  }
  int run = sm[threadIdx.x] - sum;  // exclusive prefix for this thread
  if (threadIdx.x == BLK - 1) tot[blockIdx.x] = sm[BLK - 1];
#pragma unroll
  for (int j = 0; j < 16; ++j) {
    int idx = base + j;
    if (idx < L) data[idx] = run;
    run += v[j];
  }
}

__global__ void k_scanB(int* __restrict__ tot, int m) {  // single block, m <= 4096
  __shared__ int sm[BLK];
  const int base = threadIdx.x * 16;
  int v[16];
  int sum = 0;
#pragma unroll
  for (int j = 0; j < 16; ++j) {
    int idx = base + j;
    v[j] = (idx < m) ? tot[idx] : 0;
    sum += v[j];
  }
  sm[threadIdx.x] = sum;
  __syncthreads();
  for (int off = 1; off < BLK; off <<= 1) {
    int t = (threadIdx.x >= off) ? sm[threadIdx.x - off] : 0;
    __syncthreads();
    sm[threadIdx.x] += t;
    __syncthreads();
  }
  int run = sm[threadIdx.x] - sum;
#pragma unroll
  for (int j = 0; j < 16; ++j) {
    int idx = base + j;
    if (idx < m) tot[idx] = run;
    run += v[j];
  }
}

__global__ void k_scanC(int* __restrict__ data, const int* __restrict__ tot, int L) {
  const int add = tot[blockIdx.x];
  const int base = blockIdx.x * (BLK * 16) + threadIdx.x;
#pragma unroll
  for (int j = 0; j < 16; ++j) {
    int idx = base + j * BLK;
    if (idx < L) data[idx] += add;
  }
}

__global__ void k_bs(const int* __restrict__ counts, int* __restrict__ bs,
                     int NB, int nblk, int e) {
  int b = blockIdx.x * BLK + threadIdx.x;
  if (b < NB) bs[b] = counts[(size_t)b * nblk];
  if (b == 0) bs[NB] = e;
}

// ---------- partition: fill packed edge array (bucket-grouped) ----------
__global__ void k_fill(const int* __restrict__ rows, const int* __restrict__ cols,
                       const int* __restrict__ counts, long long* __restrict__ packed,
                       int e, int NB, int nblk) {
  __shared__ int cur[NPB];
  for (int b = threadIdx.x; b < NB; b += BLK)
    cur[b] = counts[(size_t)b * nblk + blockIdx.x];
  __syncthreads();
  const int base = blockIdx.x * EPB;
#pragma unroll
  for (int k = 0; k < 16; ++k) {
    int i = base + k * BLK + threadIdx.x;
    if (i < e) {
      int r = rows[i];
      int c = cols[i];
      int p = atomicAdd(&cur[c >> 10], 1);
      packed[p] = ((long long)(unsigned)c << 32) | (unsigned)r;
    }
  }
}

// ---------- per-bucket degree -> dis = rsqrt(deg+1) ----------
__global__ void k_bdeg(const long long* __restrict__ packed, const int* __restrict__ bs,
                       float* __restrict__ dis, int n) {
  __shared__ int cnt[NPB];
  for (int j = threadIdx.x; j < NPB; j += BLK) cnt[j] = 0;
  __syncthreads();
  const int b = blockIdx.x;
  const int s = bs[b], t = bs[b + 1];
  for (int i = s + threadIdx.x; i < t; i += BLK) {
    int c = (int)(packed[i] >> 32);
    atomicAdd(&cnt[c & (NPB - 1)], 1);
  }
  __syncthreads();
  const int base = b << 10;
  for (int j = threadIdx.x; j < NPB; j += BLK) {
    int node = base + j;
    if (node < n) dis[node] = rsqrtf((float)(cnt[j] + 1));
  }
}

// ---------- node pass 1: s1 = (x @ W1) * dis ----------
__global__ void k_node1(const float* __restrict__ x, const float* __restrict__ W1,
                        const float* __restrict__ dis, float* __restrict__ s1, int n) {
  __shared__ float sx[BLK * F_INK];
  const int base = blockIdx.x * BLK;
  const int gbase = base * F_INK;
  const int lim = n * F_INK;
  for (int t = threadIdx.x; t < BLK * F_INK; t += BLK) {
    int gi = gbase + t;
    sx[t] = (gi < lim) ? x[gi] : 0.0f;
  }
  __syncthreads();
  int i = base + threadIdx.x;
  if (i >= n) return;
  float di = dis[i];
  float hw[F_HIDK];
#pragma unroll
  for (int f = 0; f < F_HIDK; ++f) hw[f] = 0.0f;
  const float* xi = &sx[threadIdx.x * F_INK];
#pragma unroll
  for (int k = 0; k < F_INK; ++k) {
    float xk = xi[k];
#pragma unroll
    for (int f = 0; f < F_HIDK; ++f) hw[f] = fmaf(xk, W1[k * F_HIDK + f], hw[f]);
  }
  float4* o = (float4*)&s1[(size_t)i * F_HIDK];
#pragma unroll
  for (int q = 0; q < 4; ++q) {
    float4 v;
    v.x = hw[q * 4 + 0] * di;
    v.y = hw[q * 4 + 1] * di;
    v.z = hw[q * 4 + 2] * di;
    v.w = hw[q * 4 + 3] * di;
    o[q] = v;
  }
}

// ---------- layer 1 aggregate (LDS tile) + fused node2 epilogue ----------
// agg = sum_{edges into tile} s1[row]; h = relu(dis*(agg+s1_self)+b1); s2 = (h@W2)*dis
__global__ void __launch_bounds__(BLK) k_agg1node2(
    const long long* __restrict__ packed, const int* __restrict__ bs,
    const float* __restrict__ s1, const float* __restrict__ dis,
    const float* __restrict__ b1, const float* __restrict__ W2,
    float* __restrict__ s2, int n) {
  __shared__ float tile[NPB * F_HIDK];  // 64 KB
  for (int j = threadIdx.x; j < NPB * F_HIDK; j += BLK) tile[j] = 0.0f;
  __syncthreads();
  const int b = blockIdx.x;
  const int s = bs[b], t = bs[b + 1];
  const int lane = threadIdx.x & 63;
  const int wid = threadIdx.x >> 6;
  const int f = lane & 15;
  for (int base = s + wid * 64; base < t; base += 4 * 64) {
    int myi = base + lane;
    long long ed = 0;
    if (myi < t) ed = packed[myi];
    int lim = t - base;  // #valid edges in this 64-round
#pragma unroll
    for (int k = 0; k < 16; ++k) {
      int sl = (lane & 48) + k;
      long long ek = __shfl(ed, sl, 64);
      if (sl < lim) {
        int r = (int)(ek & 0xffffffffLL);
        int c = (int)(ek >> 32);
        float val = s1[(size_t)r * F_HIDK + f];
        atomicAdd(&tile[(c & (NPB - 1)) * F_HIDK + f], val);
      }
    }
  }
  __syncthreads();
  // fused node2 epilogue
  const int nbase = b << 10;
  for (int j = threadIdx.x; j < NPB; j += BLK) {
    int node = nbase + j;
    if (node >= n) continue;
    float di = dis[node];
    const float4* s4 = (const float4*)&s1[(size_t)node * F_HIDK];
    const float4* a4 = (const float4*)&tile[j * F_HIDK];
    float o0 = 0.f, o1 = 0.f;
#pragma unroll
    for (int q = 0; q < 4; ++q) {
      float4 a = a4[q];
      float4 sv = s4[q];
      float va[4] = {a.x + sv.x, a.y + sv.y, a.z + sv.z, a.w + sv.w};
#pragma unroll
      for (int jj = 0; jj < 4; ++jj) {
        int ff = q * 4 + jj;
        float h = fmaxf(fmaf(di, va[jj], b1[ff]), 0.0f);
        o0 = fmaf(h, W2[ff * 2 + 0], o0);
        o1 = fmaf(h, W2[ff * 2 + 1], o1);
      }
    }
    float2 v;
    v.x = o0 * di;
    v.y = o1 * di;
    ((float2*)s2)[node] = v;
  }
}

// ---------- layer 2 aggregate (LDS tile) + fused log_softmax epilogue ----------
__global__ void __launch_bounds__(BLK) k_agg2out(
    const long long* __restrict__ packed, const int* __restrict__ bs,
    const float* __restrict__ s2, const float* __restrict__ dis,
    const float* __restrict__ b2, float* __restrict__ out, int n) {
  __shared__ float t2[NPB * 2];  // 8 KB
  for (int j = threadIdx.x; j < NPB * 2; j += BLK) t2[j] = 0.0f;
  __syncthreads();
  const int b = blockIdx.x;
  const int s = bs[b], t = bs[b + 1];
  for (int i = s + threadIdx.x; i < t; i += BLK) {
    long long ek = packed[i];
    int r = (int)(ek & 0xffffffffLL);
    int c = (int)(ek >> 32);
    float2 v = ((const float2*)s2)[r];
    atomicAdd(&t2[(c & (NPB - 1)) * 2 + 0], v.x);
    atomicAdd(&t2[(c & (NPB - 1)) * 2 + 1], v.y);
  }
  __syncthreads();
  const int nbase = b << 10;
  for (int j = threadIdx.x; j < NPB; j += BLK) {
    int node = nbase + j;
    if (node >= n) continue;
    float di = dis[node];
    float2 sv = ((const float2*)s2)[node];
    float o0 = fmaf(di, t2[j * 2 + 0] + sv.x, b2[0]);
    float o1 = fmaf(di, t2[j * 2 + 1] + sv.y, b2[1]);
    float m = fmaxf(o0, o1);
    float lse = m + logf(expf(o0 - m) + expf(o1 - m));
    float2 r;
    r.x = o0 - lse;
    r.y = o1 - lse;
    ((float2*)out)[node] = r;
  }
}

extern "C" void kernel_launch(void* const* d_in, const int* in_sizes, int n_in,
                              void* d_out, int out_size, void* d_ws, size_t ws_size,
                              hipStream_t stream) {
  const float* x  = (const float*)d_in[0];
  const float* W1 = (const float*)d_in[1];
  const float* b1 = (const float*)d_in[2];
  const float* W2 = (const float*)d_in[3];
  const float* b2 = (const float*)d_in[4];
  const int*   ei = (const int*)d_in[5];
  const int n = in_sizes[0] / F_INK;
  const int e = in_sizes[5] / 2;
  const int* rows = ei;      // edge_index[0] = source
  const int* cols = ei + e;  // edge_index[1] = target

  const int NB = (n + NPB - 1) / NPB;           // buckets
  const int nblk = (e + EPB - 1) / EPB;         // partition blocks
  const int L = NB * nblk;                      // counts matrix size
  const int gA = (L + BLK * 16 - 1) / (BLK * 16);

  char* ws = (char*)d_ws;
  size_t off = 0;
  auto alloc = [&](size_t bytes) {
    void* p = ws + off;
    off = (off + bytes + 15) & ~(size_t)15;
    return p;
  };
  float* dis          = (float*)alloc((size_t)n * 4);
  float* s1           = (float*)alloc((size_t)n * F_HIDK * 4);
  float* s2           = (float*)alloc((size_t)n * 2 * 4);
  int* counts         = (int*)alloc((size_t)L * 4);
  int* tot            = (int*)alloc((size_t)gA * 4);
  int* bs             = (int*)alloc((size_t)(NB + 1) * 4);
  long long* packed   = (long long*)alloc((size_t)e * 8);
  float* outp = (float*)d_out;

  int gn = (n + BLK - 1) / BLK;

  k_hist <<<nblk, BLK, 0, stream>>>(cols, counts, e, NB, nblk);
  k_scanA<<<gA, BLK, 0, stream>>>(counts, tot, L);
  k_scanB<<<1, BLK, 0, stream>>>(tot, gA);
  k_scanC<<<gA, BLK, 0, stream>>>(counts, tot, L);
  k_bs   <<<(NB + BLK) / BLK, BLK, 0, stream>>>(counts, bs, NB, nblk, e);
  k_fill <<<nblk, BLK, 0, stream>>>(rows, cols, counts, packed, e, NB, nblk);
  k_bdeg <<<NB, BLK, 0, stream>>>(packed, bs, dis, n);
  k_node1<<<gn, BLK, 0, stream>>>(x, W1, dis, s1, n);
  k_agg1node2<<<NB, BLK, 0, stream>>>(packed, bs, s1, dis, b1, W2, s2, n);
  k_agg2out  <<<NB, BLK, 0, stream>>>(packed, bs, s2, dis, b2, outp, n);
}

// Round 3
// 542.913 us; speedup vs baseline: 1.6196x; 1.0415x over previous
//
#include <hip/hip_runtime.h>

#define BLK 256            // generic block
#define ABLK 512           // aggregation block
#define PBLK 512           // partition block
#define PITER 32           // edges per thread in partition
#define EPB (PBLK * PITER) // 16384 edges per partition block
#define F_INK 18
#define F_HIDK 16
#define NPB 1024           // nodes per bucket

// ---------- partition: histogram (bucket-major counts matrix) ----------
__global__ __launch_bounds__(PBLK) void k_hist(const int* __restrict__ cols,
                                               int* __restrict__ counts,
                                               int e, int NB, int nblk) {
  __shared__ int hist[NPB];
  for (int j = threadIdx.x; j < NB; j += PBLK) hist[j] = 0;
  __syncthreads();
  const int base = blockIdx.x * EPB;
#pragma unroll
  for (int k = 0; k < PITER; ++k) {
    int i = base + k * PBLK + threadIdx.x;
    if (i < e) atomicAdd(&hist[cols[i] >> 10], 1);
  }
  __syncthreads();
  for (int b = threadIdx.x; b < NB; b += PBLK)
    counts[(size_t)b * nblk + blockIdx.x] = hist[b];
}

// ---------- device-wide exclusive scan over counts (L elements) ----------
__global__ void k_scanA(int* __restrict__ data, int* __restrict__ tot, int L) {
  __shared__ int sm[BLK];
  const int base = blockIdx.x * (BLK * 16) + threadIdx.x * 16;
  int v[16];
  int sum = 0;
#pragma unroll
  for (int j = 0; j < 16; ++j) {
    int idx = base + j;
    v[j] = (idx < L) ? data[idx] : 0;
    sum += v[j];
  }
  sm[threadIdx.x] = sum;
  __syncthreads();
  for (int off = 1; off < BLK; off <<= 1) {
    int t = (threadIdx.x >= off) ? sm[threadIdx.x - off] : 0;
    __syncthreads();
    sm[threadIdx.x] += t;
    __syncthreads();
  }
  int run = sm[threadIdx.x] - sum;
  if (threadIdx.x == BLK - 1) tot[blockIdx.x] = sm[BLK - 1];
#pragma unroll
  for (int j = 0; j < 16; ++j) {
    int idx = base + j;
    if (idx < L) data[idx] = run;
    run += v[j];
  }
}

__global__ void k_scanB(int* __restrict__ tot, int m) {  // single block, m <= 4096
  __shared__ int sm[BLK];
  const int base = threadIdx.x * 16;
  int v[16];
  int sum = 0;
#pragma unroll
  for (int j = 0; j < 16; ++j) {
    int idx = base + j;
    v[j] = (idx < m) ? tot[idx] : 0;
    sum += v[j];
  }
  sm[threadIdx.x] = sum;
  __syncthreads();
  for (int off = 1; off < BLK; off <<= 1) {
    int t = (threadIdx.x >= off) ? sm[threadIdx.x - off] : 0;
    __syncthreads();
    sm[threadIdx.x] += t;
    __syncthreads();
  }
  int run = sm[threadIdx.x] - sum;
#pragma unroll
  for (int j = 0; j < 16; ++j) {
    int idx = base + j;
    if (idx < m) tot[idx] = run;
    run += v[j];
  }
}

__global__ void k_scanC(int* __restrict__ data, const int* __restrict__ tot, int L) {
  const int add = tot[blockIdx.x];
  const int base = blockIdx.x * (BLK * 16) + threadIdx.x;
#pragma unroll
  for (int j = 0; j < 16; ++j) {
    int idx = base + j * BLK;
    if (idx < L) data[idx] += add;
  }
}

__global__ void k_bs(const int* __restrict__ counts, int* __restrict__ bs,
                     int NB, int nblk, int e) {
  int b = blockIdx.x * BLK + threadIdx.x;
  if (b < NB) bs[b] = counts[(size_t)b * nblk];
  if (b == 0) bs[NB] = e;
}

// ---------- partition: fill packed edge array (bucket-grouped) ----------
__global__ __launch_bounds__(PBLK) void k_fill(const int* __restrict__ rows,
                                               const int* __restrict__ cols,
                                               const int* __restrict__ counts,
                                               long long* __restrict__ packed,
                                               int e, int NB, int nblk) {
  __shared__ int cur[NPB];
  for (int b = threadIdx.x; b < NB; b += PBLK)
    cur[b] = counts[(size_t)b * nblk + blockIdx.x];
  __syncthreads();
  const int base = blockIdx.x * EPB;
#pragma unroll
  for (int k = 0; k < PITER; ++k) {
    int i = base + k * PBLK + threadIdx.x;
    if (i < e) {
      int r = rows[i];
      int c = cols[i];
      int p = atomicAdd(&cur[c >> 10], 1);
      packed[p] = ((long long)(unsigned)c << 32) | (unsigned)r;
    }
  }
}

// ---------- per-bucket degree -> dis = rsqrt(deg+1) ----------
__global__ __launch_bounds__(ABLK) void k_bdeg(const int* __restrict__ packedHi,
                                               const int* __restrict__ bs,
                                               float* __restrict__ dis, int n) {
  __shared__ int cnt[NPB];
  for (int j = threadIdx.x; j < NPB; j += ABLK) cnt[j] = 0;
  __syncthreads();
  const int b = blockIdx.x;
  const int s = bs[b], t = bs[b + 1];
  for (int i = s + threadIdx.x; i < t; i += ABLK) {
    int c = packedHi[2 * i + 1];  // high word of packed[i]
    atomicAdd(&cnt[c & (NPB - 1)], 1);
  }
  __syncthreads();
  const int base = b << 10;
  for (int j = threadIdx.x; j < NPB; j += ABLK) {
    int node = base + j;
    if (node < n) dis[node] = rsqrtf((float)(cnt[j] + 1));
  }
}

// ---------- node pass 1: s1 = (x @ W1) * dis ----------
__global__ void k_node1(const float* __restrict__ x, const float* __restrict__ W1,
                        const float* __restrict__ dis, float* __restrict__ s1, int n) {
  __shared__ float sx[BLK * F_INK];
  const int base = blockIdx.x * BLK;
  const int gbase = base * F_INK;
  const int lim = n * F_INK;
  for (int t = threadIdx.x; t < BLK * F_INK; t += BLK) {
    int gi = gbase + t;
    sx[t] = (gi < lim) ? x[gi] : 0.0f;
  }
  __syncthreads();
  int i = base + threadIdx.x;
  if (i >= n) return;
  float di = dis[i];
  float hw[F_HIDK];
#pragma unroll
  for (int f = 0; f < F_HIDK; ++f) hw[f] = 0.0f;
  const float* xi = &sx[threadIdx.x * F_INK];
#pragma unroll
  for (int k = 0; k < F_INK; ++k) {
    float xk = xi[k];
#pragma unroll
    for (int f = 0; f < F_HIDK; ++f) hw[f] = fmaf(xk, W1[k * F_HIDK + f], hw[f]);
  }
  float4* o = (float4*)&s1[(size_t)i * F_HIDK];
#pragma unroll
  for (int q = 0; q < 4; ++q) {
    float4 v;
    v.x = hw[q * 4 + 0] * di;
    v.y = hw[q * 4 + 1] * di;
    v.z = hw[q * 4 + 2] * di;
    v.w = hw[q * 4 + 3] * di;
    o[q] = v;
  }
}

// ---------- layer 1 aggregate (LDS tile, batched gathers) + fused node2 ----------
__global__ __launch_bounds__(ABLK, 4) void k_agg1node2(
    const long long* __restrict__ packed, const int* __restrict__ bs,
    const float* __restrict__ s1, const float* __restrict__ dis,
    const float* __restrict__ b1, const float* __restrict__ W2,
    float* __restrict__ s2, int n) {
  __shared__ float tile[NPB * F_HIDK];  // 64 KB
  for (int j = threadIdx.x; j < NPB * F_HIDK; j += ABLK) tile[j] = 0.0f;
  __syncthreads();
  const int b = blockIdx.x;
  const int s = bs[b], t = bs[b + 1];
  const int lane = threadIdx.x & 63;
  const int wid = threadIdx.x >> 6;      // 8 waves
  const int f = lane & 15;
  const int grp = lane >> 4;             // 4 groups of 16 lanes
  for (int base = s + wid * 64; base < t; base += 8 * 64) {
    int myi = base + lane;
    long long ed = 0;
    if (myi < t) ed = packed[myi];
    const int lim = t - base;  // #valid edges in this 64-edge window
    float v[16];
    // phase 1: issue all 16 gathers (independent, stay in flight)
#pragma unroll
    for (int k = 0; k < 16; ++k) {
      int sl = grp * 16 + k;
      long long ek = __shfl(ed, sl, 64);
      int r = (int)(ek & 0xffffffffLL);
      v[k] = s1[(size_t)r * F_HIDK + f];  // 16 lanes -> one 64B line
    }
    // phase 2: LDS accumulate
#pragma unroll
    for (int k = 0; k < 16; ++k) {
      int sl = grp * 16 + k;
      long long ek = __shfl(ed, sl, 64);
      int c = (int)(ek >> 32);
      if (sl < lim) atomicAdd(&tile[(c & (NPB - 1)) * F_HIDK + f], v[k]);
    }
  }
  __syncthreads();
  // fused node2 epilogue: h = relu(dis*(agg+s1_self)+b1); s2 = (h@W2)*dis
  const int nbase = b << 10;
  for (int j = threadIdx.x; j < NPB; j += ABLK) {
    int node = nbase + j;
    if (node >= n) continue;
    float di = dis[node];
    const float4* s4 = (const float4*)&s1[(size_t)node * F_HIDK];
    const float4* a4 = (const float4*)&tile[j * F_HIDK];
    float o0 = 0.f, o1 = 0.f;
#pragma unroll
    for (int q = 0; q < 4; ++q) {
      float4 a = a4[q];
      float4 sv = s4[q];
      float va[4] = {a.x + sv.x, a.y + sv.y, a.z + sv.z, a.w + sv.w};
#pragma unroll
      for (int jj = 0; jj < 4; ++jj) {
        int ff = q * 4 + jj;
        float h = fmaxf(fmaf(di, va[jj], b1[ff]), 0.0f);
        o0 = fmaf(h, W2[ff * 2 + 0], o0);
        o1 = fmaf(h, W2[ff * 2 + 1], o1);
      }
    }
    float2 v;
    v.x = o0 * di;
    v.y = o1 * di;
    ((float2*)s2)[node] = v;
  }
}

// ---------- layer 2 aggregate (LDS tile, 4-deep batched) + log_softmax ----------
__global__ __launch_bounds__(ABLK) void k_agg2out(
    const long long* __restrict__ packed, const int* __restrict__ bs,
    const float* __restrict__ s2, const float* __restrict__ dis,
    const float* __restrict__ b2, float* __restrict__ out, int n) {
  __shared__ float t2[NPB * 2];  // 8 KB
  for (int j = threadIdx.x; j < NPB * 2; j += ABLK) t2[j] = 0.0f;
  __syncthreads();
  const int b = blockIdx.x;
  const int s = bs[b], t = bs[b + 1];
  for (int i0 = s + threadIdx.x; i0 < t; i0 += ABLK * 4) {
    long long ed[4];
    float2 v[4];
    int ii[4];
#pragma unroll
    for (int j = 0; j < 4; ++j) {
      ii[j] = i0 + j * ABLK;
      ed[j] = (ii[j] < t) ? packed[ii[j]] : 0;
    }
#pragma unroll
    for (int j = 0; j < 4; ++j) {
      int r = (int)(ed[j] & 0xffffffffLL);
      v[j] = ((const float2*)s2)[r];
    }
#pragma unroll
    for (int j = 0; j < 4; ++j) {
      if (ii[j] < t) {
        int c = (int)(ed[j] >> 32);
        atomicAdd(&t2[(c & (NPB - 1)) * 2 + 0], v[j].x);
        atomicAdd(&t2[(c & (NPB - 1)) * 2 + 1], v[j].y);
      }
    }
  }
  __syncthreads();
  const int nbase = b << 10;
  for (int j = threadIdx.x; j < NPB; j += ABLK) {
    int node = nbase + j;
    if (node >= n) continue;
    float di = dis[node];
    float2 sv = ((const float2*)s2)[node];
    float o0 = fmaf(di, t2[j * 2 + 0] + sv.x, b2[0]);
    float o1 = fmaf(di, t2[j * 2 + 1] + sv.y, b2[1]);
    float m = fmaxf(o0, o1);
    float lse = m + logf(expf(o0 - m) + expf(o1 - m));
    float2 r;
    r.x = o0 - lse;
    r.y = o1 - lse;
    ((float2*)out)[node] = r;
  }
}

extern "C" void kernel_launch(void* const* d_in, const int* in_sizes, int n_in,
                              void* d_out, int out_size, void* d_ws, size_t ws_size,
                              hipStream_t stream) {
  const float* x  = (const float*)d_in[0];
  const float* W1 = (const float*)d_in[1];
  const float* b1 = (const float*)d_in[2];
  const float* W2 = (const float*)d_in[3];
  const float* b2 = (const float*)d_in[4];
  const int*   ei = (const int*)d_in[5];
  const int n = in_sizes[0] / F_INK;
  const int e = in_sizes[5] / 2;
  const int* rows = ei;      // edge_index[0] = source
  const int* cols = ei + e;  // edge_index[1] = target

  const int NB = (n + NPB - 1) / NPB;    // buckets
  const int nblk = (e + EPB - 1) / EPB;  // partition blocks
  const int L = NB * nblk;               // counts matrix size
  const int gA = (L + BLK * 16 - 1) / (BLK * 16);

  char* ws = (char*)d_ws;
  size_t off = 0;
  auto alloc = [&](size_t bytes) {
    void* p = ws + off;
    off = (off + bytes + 15) & ~(size_t)15;
    return p;
  };
  float* dis        = (float*)alloc((size_t)n * 4);
  float* s1         = (float*)alloc((size_t)n * F_HIDK * 4);
  float* s2         = (float*)alloc((size_t)n * 2 * 4);
  int* counts       = (int*)alloc((size_t)L * 4);
  int* tot          = (int*)alloc((size_t)gA * 4);
  int* bs           = (int*)alloc((size_t)(NB + 1) * 4);
  long long* packed = (long long*)alloc((size_t)e * 8);
  float* outp = (float*)d_out;

  int gn = (n + BLK - 1) / BLK;

  k_hist <<<nblk, PBLK, 0, stream>>>(cols, counts, e, NB, nblk);
  k_scanA<<<gA, BLK, 0, stream>>>(counts, tot, L);
  k_scanB<<<1, BLK, 0, stream>>>(tot, gA);
  k_scanC<<<gA, BLK, 0, stream>>>(counts, tot, L);
  k_bs   <<<(NB + BLK) / BLK, BLK, 0, stream>>>(counts, bs, NB, nblk, e);
  k_fill <<<nblk, PBLK, 0, stream>>>(rows, cols, counts, packed, e, NB, nblk);
  k_bdeg <<<NB, ABLK, 0, stream>>>((const int*)packed, bs, dis, n);
  k_node1<<<gn, BLK, 0, stream>>>(x, W1, dis, s1, n);
  k_agg1node2<<<NB, ABLK, 0, stream>>>(packed, bs, s1, dis, b1, W2, s2, n);
  k_agg2out  <<<NB, ABLK, 0, stream>>>(packed, bs, s2, dis, b2, outp, n);
}

// Round 4
// 533.008 us; speedup vs baseline: 1.6497x; 1.0186x over previous
//
#include <hip/hip_runtime.h>

#define BLK 256            // generic / aggregation block
#define PBLK 512           // partition block
#define PITER 32           // edges per thread in partition
#define EPB (PBLK * PITER) // 16384 edges per partition block
#define F_INK 18
#define F_HIDK 16
#define NPB 512            // nodes per bucket
#define NPB_SH 9
#define MAXNB 2048         // >= ceil(1e6/512)=1954
#define DEP 8              // gather ILP depth (edges window = 16*DEP per wave)

// ---------- partition: histogram (bucket-major counts matrix) ----------
__global__ __launch_bounds__(PBLK) void k_hist(const int* __restrict__ cols,
                                               int* __restrict__ counts,
                                               int e, int NB, int nblk) {
  __shared__ int hist[MAXNB];
  for (int j = threadIdx.x; j < NB; j += PBLK) hist[j] = 0;
  __syncthreads();
  const int base = blockIdx.x * EPB;
#pragma unroll
  for (int k = 0; k < PITER; ++k) {
    int i = base + k * PBLK + threadIdx.x;
    if (i < e) atomicAdd(&hist[cols[i] >> NPB_SH], 1);
  }
  __syncthreads();
  for (int b = threadIdx.x; b < NB; b += PBLK)
    counts[(size_t)b * nblk + blockIdx.x] = hist[b];
}

// ---------- device-wide exclusive scan over counts (L elements) ----------
__global__ void k_scanA(int* __restrict__ data, int* __restrict__ tot, int L) {
  __shared__ int sm[BLK];
  const int base = blockIdx.x * (BLK * 16) + threadIdx.x * 16;
  int v[16];
  int sum = 0;
#pragma unroll
  for (int j = 0; j < 16; ++j) {
    int idx = base + j;
    v[j] = (idx < L) ? data[idx] : 0;
    sum += v[j];
  }
  sm[threadIdx.x] = sum;
  __syncthreads();
  for (int off = 1; off < BLK; off <<= 1) {
    int t = (threadIdx.x >= off) ? sm[threadIdx.x - off] : 0;
    __syncthreads();
    sm[threadIdx.x] += t;
    __syncthreads();
  }
  int run = sm[threadIdx.x] - sum;
  if (threadIdx.x == BLK - 1) tot[blockIdx.x] = sm[BLK - 1];
#pragma unroll
  for (int j = 0; j < 16; ++j) {
    int idx = base + j;
    if (idx < L) data[idx] = run;
    run += v[j];
  }
}

__global__ void k_scanB(int* __restrict__ tot, int m) {  // single block, m <= 4096
  __shared__ int sm[BLK];
  const int base = threadIdx.x * 16;
  int v[16];
  int sum = 0;
#pragma unroll
  for (int j = 0; j < 16; ++j) {
    int idx = base + j;
    v[j] = (idx < m) ? tot[idx] : 0;
    sum += v[j];
  }
  sm[threadIdx.x] = sum;
  __syncthreads();
  for (int off = 1; off < BLK; off <<= 1) {
    int t = (threadIdx.x >= off) ? sm[threadIdx.x - off] : 0;
    __syncthreads();
    sm[threadIdx.x] += t;
    __syncthreads();
  }
  int run = sm[threadIdx.x] - sum;
#pragma unroll
  for (int j = 0; j < 16; ++j) {
    int idx = base + j;
    if (idx < m) tot[idx] = run;
    run += v[j];
  }
}

__global__ void k_scanC(int* __restrict__ data, const int* __restrict__ tot, int L) {
  const int add = tot[blockIdx.x];
  const int base = blockIdx.x * (BLK * 16) + threadIdx.x;
#pragma unroll
  for (int j = 0; j < 16; ++j) {
    int idx = base + j * BLK;
    if (idx < L) data[idx] += add;
  }
}

__global__ void k_bs(const int* __restrict__ counts, int* __restrict__ bs,
                     int NB, int nblk, int e) {
  int b = blockIdx.x * BLK + threadIdx.x;
  if (b < NB) bs[b] = counts[(size_t)b * nblk];
  if (b == 0) bs[NB] = e;
}

// ---------- partition: fill packed edge array (bucket-grouped) ----------
__global__ __launch_bounds__(PBLK) void k_fill(const int* __restrict__ rows,
                                               const int* __restrict__ cols,
                                               const int* __restrict__ counts,
                                               long long* __restrict__ packed,
                                               int e, int NB, int nblk) {
  __shared__ int cur[MAXNB];
  for (int b = threadIdx.x; b < NB; b += PBLK)
    cur[b] = counts[(size_t)b * nblk + blockIdx.x];
  __syncthreads();
  const int base = blockIdx.x * EPB;
#pragma unroll
  for (int k = 0; k < PITER; ++k) {
    int i = base + k * PBLK + threadIdx.x;
    if (i < e) {
      int r = rows[i];
      int c = cols[i];
      int p = atomicAdd(&cur[c >> NPB_SH], 1);
      packed[p] = ((long long)(unsigned)c << 32) | (unsigned)r;
    }
  }
}

// ---------- per-bucket degree -> dis = rsqrt(deg+1) ----------
__global__ __launch_bounds__(BLK) void k_bdeg(const int* __restrict__ packedHi,
                                              const int* __restrict__ bs,
                                              float* __restrict__ dis, int n) {
  __shared__ int cnt[NPB];
  for (int j = threadIdx.x; j < NPB; j += BLK) cnt[j] = 0;
  __syncthreads();
  const int b = blockIdx.x;
  const int s = bs[b], t = bs[b + 1];
  for (int i = s + threadIdx.x; i < t; i += BLK) {
    int c = packedHi[2 * i + 1];  // high word of packed[i]
    atomicAdd(&cnt[c & (NPB - 1)], 1);
  }
  __syncthreads();
  const int base = b << NPB_SH;
  for (int j = threadIdx.x; j < NPB; j += BLK) {
    int node = base + j;
    if (node < n) dis[node] = rsqrtf((float)(cnt[j] + 1));
  }
}

// ---------- node pass 1: s1 = (x @ W1) * dis ----------
__global__ void k_node1(const float* __restrict__ x, const float* __restrict__ W1,
                        const float* __restrict__ dis, float* __restrict__ s1, int n) {
  __shared__ float sx[BLK * F_INK];
  const int base = blockIdx.x * BLK;
  const int gbase = base * F_INK;
  const int lim = n * F_INK;
  for (int t = threadIdx.x; t < BLK * F_INK; t += BLK) {
    int gi = gbase + t;
    sx[t] = (gi < lim) ? x[gi] : 0.0f;
  }
  __syncthreads();
  int i = base + threadIdx.x;
  if (i >= n) return;
  float di = dis[i];
  float hw[F_HIDK];
#pragma unroll
  for (int f = 0; f < F_HIDK; ++f) hw[f] = 0.0f;
  const float* xi = &sx[threadIdx.x * F_INK];
#pragma unroll
  for (int k = 0; k < F_INK; ++k) {
    float xk = xi[k];
#pragma unroll
    for (int f = 0; f < F_HIDK; ++f) hw[f] = fmaf(xk, W1[k * F_HIDK + f], hw[f]);
  }
  float4* o = (float4*)&s1[(size_t)i * F_HIDK];
#pragma unroll
  for (int q = 0; q < 4; ++q) {
    float4 v;
    v.x = hw[q * 4 + 0] * di;
    v.y = hw[q * 4 + 1] * di;
    v.z = hw[q * 4 + 2] * di;
    v.w = hw[q * 4 + 3] * di;
    o[q] = v;
  }
}

// ---------- layer 1 aggregate: float4 gathers, 4 lanes/edge, ILP=DEP ----------
__global__ __launch_bounds__(BLK) void k_agg1node2(
    const long long* __restrict__ packed, const int* __restrict__ bs,
    const float* __restrict__ s1, const float* __restrict__ dis,
    const float* __restrict__ b1, const float* __restrict__ W2,
    float* __restrict__ s2, int n) {
  __shared__ float tile[NPB * F_HIDK];  // 32 KB
  for (int j = threadIdx.x; j < NPB * F_HIDK; j += BLK) tile[j] = 0.0f;
  __syncthreads();
  const int b = blockIdx.x;
  const int s = bs[b], t = bs[b + 1];
  const int lane = threadIdx.x & 63;
  const int wid = threadIdx.x >> 6;   // 4 waves
  const int esub = lane >> 2;         // edge slot 0..15 within a 16-edge group
  const int q = lane & 3;             // which 16B chunk of the 64B row
  const int W = 16 * DEP;             // edges per wave-iteration
  for (int base = s + wid * W; base < t; base += 4 * W) {
    long long pk[DEP];
    float4 v[DEP];
#pragma unroll
    for (int d = 0; d < DEP; ++d) {
      int idx = base + d * 16 + esub;
      pk[d] = packed[min(idx, t - 1)];   // t>s guaranteed inside loop
    }
#pragma unroll
    for (int d = 0; d < DEP; ++d) {
      int r = (int)(pk[d] & 0xffffffffLL);
      v[d] = *(const float4*)&s1[(size_t)r * F_HIDK + q * 4];
    }
#pragma unroll
    for (int d = 0; d < DEP; ++d) {
      int idx = base + d * 16 + esub;
      if (idx < t) {
        int c = (int)(pk[d] >> 32) & (NPB - 1);
        float* tp = &tile[c * F_HIDK + q * 4];
        atomicAdd(tp + 0, v[d].x);
        atomicAdd(tp + 1, v[d].y);
        atomicAdd(tp + 2, v[d].z);
        atomicAdd(tp + 3, v[d].w);
      }
    }
  }
  __syncthreads();
  // fused node2 epilogue: h = relu(dis*(agg+s1_self)+b1); s2 = (h@W2)*dis
  const int nbase = b << NPB_SH;
  for (int j = threadIdx.x; j < NPB; j += BLK) {
    int node = nbase + j;
    if (node >= n) continue;
    float di = dis[node];
    const float4* s4 = (const float4*)&s1[(size_t)node * F_HIDK];
    const float4* a4 = (const float4*)&tile[j * F_HIDK];
    float o0 = 0.f, o1 = 0.f;
#pragma unroll
    for (int qq = 0; qq < 4; ++qq) {
      float4 a = a4[qq];
      float4 sv = s4[qq];
      float va[4] = {a.x + sv.x, a.y + sv.y, a.z + sv.z, a.w + sv.w};
#pragma unroll
      for (int jj = 0; jj < 4; ++jj) {
        int ff = qq * 4 + jj;
        float h = fmaxf(fmaf(di, va[jj], b1[ff]), 0.0f);
        o0 = fmaf(h, W2[ff * 2 + 0], o0);
        o1 = fmaf(h, W2[ff * 2 + 1], o1);
      }
    }
    float2 v;
    v.x = o0 * di;
    v.y = o1 * di;
    ((float2*)s2)[node] = v;
  }
}

// ---------- layer 2 aggregate (LDS tile, 4-deep batched) + log_softmax ----------
__global__ __launch_bounds__(BLK) void k_agg2out(
    const long long* __restrict__ packed, const int* __restrict__ bs,
    const float* __restrict__ s2, const float* __restrict__ dis,
    const float* __restrict__ b2, float* __restrict__ out, int n) {
  __shared__ float t2[NPB * 2];  // 4 KB
  for (int j = threadIdx.x; j < NPB * 2; j += BLK) t2[j] = 0.0f;
  __syncthreads();
  const int b = blockIdx.x;
  const int s = bs[b], t = bs[b + 1];
  for (int i0 = s + threadIdx.x; i0 < t; i0 += BLK * 4) {
    long long ed[4];
    float2 v[4];
    int ii[4];
#pragma unroll
    for (int j = 0; j < 4; ++j) {
      ii[j] = i0 + j * BLK;
      ed[j] = packed[min(ii[j], t - 1)];
    }
#pragma unroll
    for (int j = 0; j < 4; ++j) {
      int r = (int)(ed[j] & 0xffffffffLL);
      v[j] = ((const float2*)s2)[r];
    }
#pragma unroll
    for (int j = 0; j < 4; ++j) {
      if (ii[j] < t) {
        int c = (int)(ed[j] >> 32) & (NPB - 1);
        atomicAdd(&t2[c * 2 + 0], v[j].x);
        atomicAdd(&t2[c * 2 + 1], v[j].y);
      }
    }
  }
  __syncthreads();
  const int nbase = b << NPB_SH;
  for (int j = threadIdx.x; j < NPB; j += BLK) {
    int node = nbase + j;
    if (node >= n) continue;
    float di = dis[node];
    float2 sv = ((const float2*)s2)[node];
    float o0 = fmaf(di, t2[j * 2 + 0] + sv.x, b2[0]);
    float o1 = fmaf(di, t2[j * 2 + 1] + sv.y, b2[1]);
    float m = fmaxf(o0, o1);
    float lse = m + logf(expf(o0 - m) + expf(o1 - m));
    float2 r;
    r.x = o0 - lse;
    r.y = o1 - lse;
    ((float2*)out)[node] = r;
  }
}

extern "C" void kernel_launch(void* const* d_in, const int* in_sizes, int n_in,
                              void* d_out, int out_size, void* d_ws, size_t ws_size,
                              hipStream_t stream) {
  const float* x  = (const float*)d_in[0];
  const float* W1 = (const float*)d_in[1];
  const float* b1 = (const float*)d_in[2];
  const float* W2 = (const float*)d_in[3];
  const float* b2 = (const float*)d_in[4];
  const int*   ei = (const int*)d_in[5];
  const int n = in_sizes[0] / F_INK;
  const int e = in_sizes[5] / 2;
  const int* rows = ei;      // edge_index[0] = source
  const int* cols = ei + e;  // edge_index[1] = target

  const int NB = (n + NPB - 1) / NPB;    // buckets (1954)
  const int nblk = (e + EPB - 1) / EPB;  // partition blocks
  const int L = NB * nblk;               // counts matrix size
  const int gA = (L + BLK * 16 - 1) / (BLK * 16);

  char* ws = (char*)d_ws;
  size_t off = 0;
  auto alloc = [&](size_t bytes) {
    void* p = ws + off;
    off = (off + bytes + 15) & ~(size_t)15;
    return p;
  };
  float* dis        = (float*)alloc((size_t)n * 4);
  float* s1         = (float*)alloc((size_t)n * F_HIDK * 4);
  float* s2         = (float*)alloc((size_t)n * 2 * 4);
  int* counts       = (int*)alloc((size_t)L * 4);
  int* tot          = (int*)alloc((size_t)gA * 4);
  int* bs           = (int*)alloc((size_t)(NB + 1) * 4);
  long long* packed = (long long*)alloc((size_t)e * 8);
  float* outp = (float*)d_out;

  int gn = (n + BLK - 1) / BLK;

  k_hist <<<nblk, PBLK, 0, stream>>>(cols, counts, e, NB, nblk);
  k_scanA<<<gA, BLK, 0, stream>>>(counts, tot, L);
  k_scanB<<<1, BLK, 0, stream>>>(tot, gA);
  k_scanC<<<gA, BLK, 0, stream>>>(counts, tot, L);
  k_bs   <<<(NB + BLK - 1) / BLK, BLK, 0, stream>>>(counts, bs, NB, nblk, e);
  k_fill <<<nblk, PBLK, 0, stream>>>(rows, cols, counts, packed, e, NB, nblk);
  k_bdeg <<<NB, BLK, 0, stream>>>((const int*)packed, bs, dis, n);
  k_node1<<<gn, BLK, 0, stream>>>(x, W1, dis, s1, n);
  k_agg1node2<<<NB, BLK, 0, stream>>>(packed, bs, s1, dis, b1, W2, s2, n);
  k_agg2out  <<<NB, BLK, 0, stream>>>(packed, bs, s2, dis, b2, outp, n);
}